// Round 7
// baseline (20649.716 us; speedup 1.0000x reference)
//
#include <hip/hip_runtime.h>
#include <hip/hip_bf16.h>

// ---------------- problem constants ----------------
#define BB 8192
#define TT 32
#define DD 12
#define ZZ 128
#define HE 512
#define HD 1024
#define KEp 640    // 512 + 12 -> padded to 20 x 32
#define KDp 1152   // 1024 + 12 -> padded to 36 x 32

typedef unsigned short u16;
typedef __attribute__((ext_vector_type(8))) short bf16x8;
typedef __attribute__((ext_vector_type(4))) float f32x4;

__device__ __forceinline__ u16 f2bf(float f) {
    __hip_bfloat16 h = __float2bfloat16(f);
    return *reinterpret_cast<u16*>(&h);
}
__device__ __forceinline__ float bf2f(u16 u) {
    __hip_bfloat16 h;
    *reinterpret_cast<u16*>(&h) = u;
    return __bfloat162float(h);
}
__device__ __forceinline__ float sigmf(float x) { return 1.f / (1.f + __expf(-x)); }
__device__ __forceinline__ float tanh_(float x) {
    float ax = fabsf(x);
    float e = __expf(-2.f * ax);
    float t = (1.f - e) / (1.f + e);
    return copysignf(t, x);
}

__device__ __forceinline__ void gload_lds16(const void* g, void* l) {
    __builtin_amdgcn_global_load_lds(
        (const __attribute__((address_space(1))) void*)g,
        (__attribute__((address_space(3))) void*)l,
        16, 0, 0);
}

#define BAR() asm volatile("s_barrier" ::: "memory")
#define VMCNT(n) asm volatile("s_waitcnt vmcnt(" #n ")" ::: "memory")

// ============================================================================
// 256x256 GEMM, BK=32, 64KB LDS -> 2 blocks/CU, fused LSTM epilogue.
// C[M][N] = A[M][Kp] * W[N][Kp]^T, bf16 row-major, Kp = 32*NT (NT even).
// 512 threads = 8 waves (2M x 4N); per-wave output 128x64.
// LDS: 4 regions [256 rows][32 k] bf16 (16KB each) = 64KB: (dbuf d0/d1, A/B).
// Conflict-free layout at 64B row stride (row-pair interleave + XOR, both
// sides per rule#21): logical (row r, 16B-slot s in [0,4)) lives at phys byte
//   (r>>1)*128 + (r&1)*64 + (s ^ ((r>>1)&3))*16.
// A wave's b128 fragment read (16 consecutive rows, one slot) touches 8
// distinct 4-bank groups x 2 lanes = 2-way = free (m136). global_load_lds
// stays linear: thread tid's LDS dest tid*16B corresponds to logical
//   r = 2*(tid>>3) + ((tid>>2)&1), s = (tid&3) ^ ((tid>>3)&3)
// which is applied to the per-lane GLOBAL source address (involution).
// Pipeline (iter n consumes K-32 tiles 2n->d0, 2n+1->d1; 4 phases, counted
// vmcnt, never 0 mid-loop):
//   p0: stage t(2n+1)->d1 (4 loads); vmcnt(4) [drains t(2n), keeps t(2n+1)];
//       ds_read d0(mh0 A + B); BAR; 16 MFMA; BAR
//   p1: ds_read d0(mh1); BAR; 16 MFMA; BAR            [d0 retired]
//   p2: stage t(2n+2)->d0; vmcnt(4) [drains t(2n+1)]; ds_read d1(mh0+B);
//       BAR; 16 MFMA; BAR
//   p3: ds_read d1(mh1); BAR; 16 MFMA; BAR            [d1 retired]
// Buffer overwrite is safe: each stage targets a region whose last reads
// completed before the previous phase's end-barrier (lgkmcnt precedes MFMA).
// MODE 1: encoder LSTM epilogue (+ hn capture + stage x[t+1])
// MODE 2: decoder LSTM epilogue (+ stage x[t])
// ============================================================================
#define REGION(dd, mat) (((dd)*2 + (mat)) * 8192)

#define STAGE(dd, mat, ktile) do { \
    const u16* Gp_ = (mat) ? W : A; \
    const int rb_ = (mat) ? bn : bm; \
    const int r_ = 2*(tid >> 3) + ((tid >> 2) & 1); \
    const int s_ = (tid & 3) ^ ((tid >> 3) & 3); \
    u16* dst_ = &lds[REGION(dd, mat) + tid*8]; \
    const u16* src_ = Gp_ + (size_t)(rb_ + r_) * Kp + (ktile)*32 + s_*8; \
    gload_lds16(src_,                    dst_); \
    gload_lds16(src_ + (size_t)128 * Kp, dst_ + 4096); \
} while (0)

#define LDA4(mh, dd) do { \
    const u16* bp_ = &lds[REGION(dd, 0)]; \
    const int sk_ = lane >> 4; \
    _Pragma("unroll") \
    for (int i_ = 0; i_ < 4; ++i_) { \
        const int lr_ = wm*128 + (mh)*64 + i_*16 + (lane & 15); \
        af[i_] = *(const bf16x8*)&bp_[(lr_>>1)*64 + (lr_&1)*32 + ((sk_ ^ ((lr_>>1)&3)) << 3)]; \
    } \
} while (0)

#define LDB4(dd) do { \
    const u16* bp_ = &lds[REGION(dd, 1)]; \
    const int sk_ = lane >> 4; \
    _Pragma("unroll") \
    for (int j_ = 0; j_ < 4; ++j_) { \
        const int lr_ = wn*64 + j_*16 + (lane & 15); \
        bf[j_] = *(const bf16x8*)&bp_[(lr_>>1)*64 + (lr_&1)*32 + ((sk_ ^ ((lr_>>1)&3)) << 3)]; \
    } \
} while (0)

#define MFMA16(mh) do { \
    __builtin_amdgcn_s_setprio(1); \
    _Pragma("unroll") \
    for (int i_ = 0; i_ < 4; ++i_) \
    _Pragma("unroll") \
    for (int j_ = 0; j_ < 4; ++j_) \
        acc[(mh)*4 + i_][j_] = __builtin_amdgcn_mfma_f32_16x16x32_bf16( \
            af[i_], bf[j_], acc[(mh)*4 + i_][j_], 0, 0, 0); \
    __builtin_amdgcn_s_setprio(0); \
} while (0)

template<int MODE>
__global__ __launch_bounds__(512, 4)
void gemm256(const u16* __restrict__ A, const u16* __restrict__ W,
             int Kp, int NT, int H,
             float* __restrict__ Cst, u16* __restrict__ Aout,
             const float* __restrict__ bias, const int* __restrict__ lens,
             u16* __restrict__ HN, const float* __restrict__ X, int t)
{
    extern __shared__ u16 lds[];
    const int tid  = threadIdx.x;
    const int lane = tid & 63;
    const int wid  = tid >> 6;
    const int wm = wid >> 2, wn = wid & 3;
    const int bm = blockIdx.x * 256;
    const int bn = blockIdx.y * 256;

    f32x4 acc[8][4] = {};
    bf16x8 af[4], bf[4];

    // prologue: tile 0 -> d0
    STAGE(0, 0, 0); STAGE(0, 1, 0);
    VMCNT(0);
    BAR();

    const int NI = NT >> 1;
    for (int n = 0; n < NI; ++n) {
        const int t1 = 2*n + 1, t2 = 2*n + 2;
        const bool more = (t2 < NT);
        // p0: stage t1->d1; drain t(2n) (keep t1); read d0 mh0+B
        STAGE(1, 0, t1); STAGE(1, 1, t1);
        VMCNT(4);
        LDA4(0, 0); LDB4(0);
        BAR(); MFMA16(0); BAR();
        // p1: read d0 mh1
        LDA4(1, 0);
        BAR(); MFMA16(1); BAR();          // d0 retired
        // p2: stage t2->d0; drain t1 (keep t2); read d1 mh0+B
        if (more) { STAGE(0, 0, t2); STAGE(0, 1, t2); VMCNT(4); }
        else      { VMCNT(0); }
        LDA4(0, 1); LDB4(1);
        BAR(); MFMA16(0); BAR();
        // p3: read d1 mh1
        LDA4(1, 1);
        BAR(); MFMA16(1); BAR();          // d1 retired
    }

    // ---- fused LSTM epilogue (gate-interleaved weights) ----
    // acc[a] covers rows wm*128 + a*16 .. +15 (mh*64 + i*16 == (mh*4+i)*16).
    const int hcol = ((bn >> 6) + wn) * 16 + (lane & 15);
    const float bI = bias[hcol];
    const float bF = bias[H + hcol];
    const float bG = bias[2 * H + hcol];
    const float bO = bias[3 * H + hcol];
#pragma unroll
    for (int i = 0; i < 8; ++i) {
        const int rbase = bm + wm * 128 + i * 16 + (lane >> 4) * 4;
#pragma unroll
        for (int q = 0; q < 4; ++q) {
            const int r = rbase + q;
            float iv = sigmf(acc[i][0][q] + bI);
            float fv = sigmf(acc[i][1][q] + bF);
            float gv = tanh_(acc[i][2][q] + bG);
            float ov = sigmf(acc[i][3][q] + bO);
            float cn = fv * Cst[(size_t)r * H + hcol] + iv * gv;
            float h  = ov * tanh_(cn);
            Cst[(size_t)r * H + hcol] = cn;
            Aout[(size_t)r * Kp + hcol] = f2bf(h);
            if (MODE == 1) {
                int L = lens[r]; L = (L < 1) ? 1 : (L > TT ? TT : L);
                if (t == L - 1) HN[(size_t)r * H + hcol] = f2bf(h);
            }
        }
    }
    // stage next-step x into Aout x-columns (one block column does it)
    const int tx = (MODE == 1) ? t + 1 : t;
    if (bn == 0 && tx < TT) {
        for (int ii = tid; ii < 256 * DD; ii += 512) {
            const int rr = ii / DD, d = ii - rr * DD;
            const int r = bm + rr;
            Aout[(size_t)r * Kp + H + d] = f2bf(X[((size_t)r * TT + tx) * DD + d]);
        }
    }
}

// ---------------- plain 128x128 GEMM (small matmuls): C = A * W^T ----------
__global__ __launch_bounds__(256, 2)
void gemm_bt(const u16* __restrict__ A, const u16* __restrict__ W,
             float* __restrict__ C, int N, int K)
{
    __shared__ u16 As[128 * 64];
    __shared__ u16 Ws[128 * 64];
    const int tid  = threadIdx.x;
    const int lane = tid & 63;
    const int wave = tid >> 6;
    const int wm = wave >> 1, wn = wave & 1;
    const int bm = blockIdx.x * 128;
    const int bn = blockIdx.y * 128;

    f32x4 acc[4][4] = {};
    const int lrow = lane >> 3;
    const int lcol = (lane & 7) * 8;

    for (int kt = 0; kt < K; kt += 64) {
#pragma unroll
        for (int c2 = 0; c2 < 4; ++c2) {
            const int chunk = wave * 4 + c2;
            const int row = chunk * 8 + lrow;
            gload_lds16(A + (size_t)(bm + row) * K + kt + lcol, &As[chunk * 512]);
            gload_lds16(W + (size_t)(bn + row) * K + kt + lcol, &Ws[chunk * 512]);
        }
        __syncthreads();
#pragma unroll
        for (int ks = 0; ks < 2; ++ks) {
            bf16x8 af[4], wf[4];
            const int ko = ks * 32 + (lane >> 4) * 8;
            const int rA = wm * 64 + (lane & 15);
            const int rW = wn * 64 + (lane & 15);
#pragma unroll
            for (int i = 0; i < 4; ++i)
                af[i] = *(const bf16x8*)&As[(rA + i * 16) * 64 + ko];
#pragma unroll
            for (int i = 0; i < 4; ++i)
                wf[i] = *(const bf16x8*)&Ws[(rW + i * 16) * 64 + ko];
#pragma unroll
            for (int i = 0; i < 4; ++i)
#pragma unroll
                for (int j = 0; j < 4; ++j)
                    acc[i][j] = __builtin_amdgcn_mfma_f32_16x16x32_bf16(
                        af[i], wf[j], acc[i][j], 0, 0, 0);
        }
        __syncthreads();
    }
    const int r0 = bm + wm * 64 + (lane >> 4) * 4;
    const int c0 = bn + wn * 64 + (lane & 15);
#pragma unroll
    for (int i = 0; i < 4; ++i)
#pragma unroll
        for (int j = 0; j < 4; ++j) {
            float* Cp = C + (size_t)(r0 + i * 16) * N + c0 + j * 16;
#pragma unroll
            for (int q = 0; q < 4; ++q)
                Cp[(size_t)q * N] = acc[i][j][q];
        }
}

// ---------------- gate-interleaved weight concat (padded K) ----------------
// n' = 64*(j>>4) + 16*gate + (j&15); row = [Whh[gate*H+j] | Wih[gate*H+j] | 0]
__global__ void prep_wg(const float* __restrict__ Whh, const float* __restrict__ Wih,
                        u16* __restrict__ dst, int H, int Kc, int total)
{
    int idx = blockIdx.x * 256 + threadIdx.x;
    if (idx >= total) return;
    int np = idx / Kc, k = idx - np * Kc;
    int jblk = np >> 6, rem = np & 63;
    int gate = rem >> 4, jl = rem & 15;
    int j = jblk * 16 + jl;
    int srow = gate * H + j;
    float v = 0.f;
    if (k < H) v = Whh[(size_t)srow * H + k];
    else if (k < H + DD) v = Wih[srow * DD + (k - H)];
    dst[idx] = f2bf(v);
}

// ---------------- plain stacked concat (bf16): [W0; W1] ----------------
__global__ void prep_cat(const float* __restrict__ W0, const float* __restrict__ W1,
                         u16* __restrict__ dst, int rows0, int K, int total)
{
    int idx = blockIdx.x * 256 + threadIdx.x;
    if (idx >= total) return;
    int n = idx / K, k = idx - n * K;
    float v = (n < rows0) ? W0[(size_t)n * K + k] : W1[(size_t)(n - rows0) * K + k];
    dst[idx] = f2bf(v);
}

__global__ void prep_bf(const float* __restrict__ src, u16* __restrict__ dst, int total)
{
    int idx = blockIdx.x * 256 + threadIdx.x;
    if (idx < total) dst[idx] = f2bf(src[idx]);
}

// ---------------- encoder init: h=0, x col = x[:,0,:], pad=0; c=0 ----------
__global__ void init_enc(u16* __restrict__ A, float* __restrict__ c, const float* __restrict__ x)
{
    int idx = blockIdx.x * 256 + threadIdx.x;   // BB*KEp
    int b = idx / KEp, j = idx - b * KEp;
    u16 v = 0;
    if (j >= HE && j < HE + DD) v = f2bf(x[(size_t)b * (TT * DD) + (j - HE)]);
    A[idx] = v;
    if (j < HE) c[(size_t)b * HE + j] = 0.f;
}

// ---------------- zero pad columns [lo, lo+n) of A[BB][ldK] ----------------
__global__ void zero_pads(u16* __restrict__ A, int ldK, int lo, int n, int total)
{
    int idx = blockIdx.x * 256 + threadIdx.x;
    if (idx >= total) return;
    int b = idx / n, j = idx - b * n;
    A[(size_t)b * ldK + lo + j] = 0;
}

// ---------------- z from MV = [mu | lv] fp32 ----------------
__global__ void z_comp(const float* __restrict__ MV, const float* __restrict__ bmu,
                       const float* __restrict__ blv, const float* __restrict__ eps,
                       float* __restrict__ out, u16* __restrict__ Zbf)
{
    int idx = blockIdx.x * 256 + threadIdx.x;   // BB*ZZ
    int b = idx >> 7, zc = idx & (ZZ - 1);
    float mu = MV[(size_t)b * 256 + zc] + bmu[zc];
    float lv = MV[(size_t)b * 256 + ZZ + zc] + blv[zc];
    float z = mu + eps[idx] * __expf(0.5f * lv);
    const size_t XR = (size_t)BB * TT * DD;
    out[XR + idx] = mu;
    out[XR + (size_t)BB * ZZ + idx] = lv;
    out[XR + 2 * (size_t)BB * ZZ + idx] = z;
    Zbf[idx] = f2bf(z);
}

// ---------------- decoder state init from HC = [h0pre | c0pre] -------------
__global__ void hc_init(const float* __restrict__ HC, const float* __restrict__ bh0,
                        const float* __restrict__ bc0, u16* __restrict__ A,
                        float* __restrict__ c)
{
    int idx = blockIdx.x * 256 + threadIdx.x;   // BB*HD
    int b = idx >> 10, j = idx & (HD - 1);
    float h0 = tanh_(HC[(size_t)b * 2048 + j] + bh0[j]);
    float c0 = tanh_(HC[(size_t)b * 2048 + HD + j] + bc0[j]);
    A[(size_t)b * KDp + j] = f2bf(h0);
    c[idx] = c0;
}

// ---------------- decoder x-col init: start token + zero pad to KDp --------
__global__ void init_dec(u16* __restrict__ A, const float* __restrict__ st)
{
    int idx = blockIdx.x * 256 + threadIdx.x;   // BB*128
    int b = idx >> 7, j = idx & 127;
    A[(size_t)b * KDp + HD + j] = (j < DD) ? f2bf(st[j]) : (u16)0;
}

// ---------------- output projection: wave per row, butterfly reduce --------
__global__ void outproj2(const u16* __restrict__ A, const u16* __restrict__ Wb,
                         const float* __restrict__ bout, float* __restrict__ xr, int t)
{
    int gid = blockIdx.x * 256 + threadIdx.x;
    int b = gid >> 6;
    int lane = threadIdx.x & 63;
    const u16* h = A + (size_t)b * KDp;
    const int k0 = lane * 16;
    bf16x8 h0 = *(const bf16x8*)&h[k0];
    bf16x8 h1 = *(const bf16x8*)&h[k0 + 8];
    float hv[16];
#pragma unroll
    for (int k = 0; k < 8; ++k) { hv[k] = bf2f((u16)h0[k]); hv[k + 8] = bf2f((u16)h1[k]); }
    float acc[DD];
#pragma unroll
    for (int d = 0; d < DD; ++d) {
        const u16* w = Wb + d * HD + k0;
        bf16x8 w0 = *(const bf16x8*)&w[0];
        bf16x8 w1 = *(const bf16x8*)&w[8];
        float a = 0.f;
#pragma unroll
        for (int k = 0; k < 8; ++k)
            a += hv[k] * bf2f((u16)w0[k]) + hv[k + 8] * bf2f((u16)w1[k]);
        acc[d] = a;
    }
#pragma unroll
    for (int off = 32; off > 0; off >>= 1)
#pragma unroll
        for (int d = 0; d < DD; ++d)
            acc[d] += __shfl_xor(acc[d], off);
    if (lane < DD)
        xr[((size_t)b * TT + t) * DD + lane] = acc[lane] + bout[lane];
}

// ---------------- launch ----------------
extern "C" void kernel_launch(void* const* d_in, const int* in_sizes, int n_in,
                              void* d_out, int out_size, void* d_ws, size_t ws_size,
                              hipStream_t stream)
{
    const float* x    = (const float*)d_in[0];
    const int*   lens = (const int*)d_in[1];
    const float* eps  = (const float*)d_in[2];
    const float* Wihe = (const float*)d_in[3];
    const float* Whhe = (const float*)d_in[4];
    const float* be   = (const float*)d_in[5];
    const float* Wmu  = (const float*)d_in[6];
    const float* bmu  = (const float*)d_in[7];
    const float* Wlv  = (const float*)d_in[8];
    const float* blv  = (const float*)d_in[9];
    const float* Wh0  = (const float*)d_in[10];
    const float* bh0  = (const float*)d_in[11];
    const float* Wc0  = (const float*)d_in[12];
    const float* bc0  = (const float*)d_in[13];
    const float* st   = (const float*)d_in[14];
    const float* Wihd = (const float*)d_in[15];
    const float* Whhd = (const float*)d_in[16];
    const float* bd   = (const float*)d_in[17];
    const float* Wout = (const float*)d_in[18];
    const float* bout = (const float*)d_in[19];
    float* out = (float*)d_out;

    char* ws = (char*)d_ws;
    size_t o = 0;
    u16*   WCE = (u16*)(ws + o); o += (size_t)2048 * KEp * 2;  //  2,621,440
    u16*   WCD = (u16*)(ws + o); o += (size_t)4096 * KDp * 2;  //  9,437,184
    u16*   WMV = (u16*)(ws + o); o += (size_t)256 * 512 * 2;   //    262,144
    u16*   WHC = (u16*)(ws + o); o += (size_t)2048 * 128 * 2;  //    524,288
    u16*   WOB = (u16*)(ws + o); o += 32768;
    u16*   AE0 = (u16*)(ws + o); o += (size_t)BB * KEp * 2;    // 10,485,760
    u16*   AE1 = (u16*)(ws + o); o += (size_t)BB * KEp * 2;
    u16*   AD0 = (u16*)(ws + o); o += (size_t)BB * KDp * 2;    // 18,874,368
    u16*   AD1 = (u16*)(ws + o); o += (size_t)BB * KDp * 2;
    float* CE  = (float*)(ws + o); o += (size_t)BB * HE * 4;   // 16,777,216
    float* CD  = (float*)(ws + o); o += (size_t)BB * HD * 4;   // 33,554,432
    u16*   HNb = (u16*)(ws + o); o += (size_t)BB * HE * 2;     //  8,388,608
    float* MV  = (float*)(ws + o); o += (size_t)BB * 256 * 4;  //  8,388,608
    u16*   Zbf = (u16*)(ws + o); o += (size_t)BB * ZZ * 2;     //  2,097,152
    float* HC  = (float*)(ws + o); o += (size_t)BB * 2048 * 4; // 67,108,864
    // total ~216 MB

    hipFuncSetAttribute((const void*)gemm256<1>,
                        hipFuncAttributeMaxDynamicSharedMemorySize, 65536);
    hipFuncSetAttribute((const void*)gemm256<2>,
                        hipFuncAttributeMaxDynamicSharedMemorySize, 65536);

    prep_wg<<<(2048 * KEp + 255) / 256, 256, 0, stream>>>(Whhe, Wihe, WCE, HE, KEp, 2048 * KEp);
    prep_wg<<<(4096 * KDp + 255) / 256, 256, 0, stream>>>(Whhd, Wihd, WCD, HD, KDp, 4096 * KDp);
    prep_cat<<<(256 * 512 + 255) / 256, 256, 0, stream>>>(Wmu, Wlv, WMV, ZZ, HE, 256 * 512);
    prep_cat<<<(2048 * 128 + 255) / 256, 256, 0, stream>>>(Wh0, Wc0, WHC, HD, ZZ, 2048 * 128);
    prep_bf<<<(12 * HD + 255) / 256, 256, 0, stream>>>(Wout, WOB, 12 * HD);
    init_enc<<<(BB * KEp) / 256, 256, 0, stream>>>(AE0, CE, x);
    zero_pads<<<(BB * 116 + 255) / 256, 256, 0, stream>>>(AE1, KEp, HE + DD, 116, BB * 116);
    zero_pads<<<(BB * 116 + 255) / 256, 256, 0, stream>>>(AD1, KDp, HD + DD, 116, BB * 116);

    u16* AE[2] = {AE0, AE1};
    for (int t = 0; t < TT; ++t) {
        gemm256<1><<<dim3(BB / 256, 2048 / 256), 512, 65536, stream>>>(
            AE[t & 1], WCE, KEp, 20, HE, CE, AE[1 - (t & 1)], be, lens, HNb, x, t);
    }

    gemm_bt<<<dim3(BB / 128, 256 / 128), 256, 0, stream>>>(HNb, WMV, MV, 256, 512);
    z_comp<<<(BB * ZZ) / 256, 256, 0, stream>>>(MV, bmu, blv, eps, out, Zbf);
    gemm_bt<<<dim3(BB / 128, 2048 / 128), 256, 0, stream>>>(Zbf, WHC, HC, 2048, 128);
    hc_init<<<(BB * HD) / 256, 256, 0, stream>>>(HC, bh0, bc0, AD0, CD);
    init_dec<<<(BB * 128) / 256, 256, 0, stream>>>(AD0, st);

    u16* AD[2] = {AD0, AD1};
    for (int t = 0; t < TT; ++t) {
        gemm256<2><<<dim3(BB / 256, 4096 / 256), 512, 65536, stream>>>(
            AD[t & 1], WCD, KDp, 36, HD, CD, AD[1 - (t & 1)], bd, nullptr, nullptr, x, t);
        outproj2<<<(BB * 64) / 256, 256, 0, stream>>>(AD[1 - (t & 1)], WOB, bout, out, t);
    }
}

// Round 8
// 4862.368 us; speedup vs baseline: 4.2468x; 4.2468x over previous
//
#include <hip/hip_runtime.h>
#include <hip/hip_bf16.h>

// ---------------- problem constants ----------------
#define BB 8192
#define TT 32
#define DD 12
#define ZZ 128
#define HE 512
#define HD 1024
#define KEp 640    // 512 + 12 -> padded to 10 x 64
#define KDp 1152   // 1024 + 12 -> padded to 18 x 64

typedef unsigned short u16;
typedef __attribute__((ext_vector_type(8))) short bf16x8;
typedef __attribute__((ext_vector_type(4))) float f32x4;

__device__ __forceinline__ u16 f2bf(float f) {
    __hip_bfloat16 h = __float2bfloat16(f);
    return *reinterpret_cast<u16*>(&h);
}
__device__ __forceinline__ float bf2f(u16 u) {
    __hip_bfloat16 h;
    *reinterpret_cast<u16*>(&h) = u;
    return __bfloat162float(h);
}
__device__ __forceinline__ float sigmf(float x) { return 1.f / (1.f + __expf(-x)); }
__device__ __forceinline__ float tanh_(float x) {
    float ax = fabsf(x);
    float e = __expf(-2.f * ax);
    float t = (1.f - e) / (1.f + e);
    return copysignf(t, x);
}

__device__ __forceinline__ void gload_lds16(const void* g, void* l) {
    __builtin_amdgcn_global_load_lds(
        (const __attribute__((address_space(1))) void*)g,
        (__attribute__((address_space(3))) void*)l,
        16, 0, 0);
}

#define BAR() asm volatile("s_barrier" ::: "memory")
#define VMCNT(n) asm volatile("s_waitcnt vmcnt(" #n ")" ::: "memory")

// ============================================================================
// 256x256 GEMM, 4-phase / 32-MFMA-per-barrier, XOR-swizzled LDS, fused LSTM
// epilogue.  C[M][N] = A[M][Kp] * W[N][Kp]^T, bf16 row-major, Kp = 64*NT.
// 512 threads = 8 waves (2M x 4N); per-wave output 128x64; acc = 128 f32
// (AGPR), af[8]+bf[4] operands -> ~190 total regs, fits (512,2). 1 block/CU.
// LDS: 4 regions [256 rows][64 k] bf16 (32KB each) = 128KB: (dbuf d0/d1, A/B).
// Swizzle (round-6-proven, conflicts==0): within a 128B row, 16B slot s at
// row r holds global k-slot s^(r&7); stage keeps LDS linear and applies the
// involution to the per-lane GLOBAL source (rule #21 both-sides).
// Pipeline per iter n (d0 = K64-tile 2n, d1 = tile 2n+1), counted vmcnt:
//   p0: stage t(2n+1)->d1 (8 gloads); VMCNT(8) [drains t(2n)->d0, keeps new];
//       ds_read d0.kh0 (A 8 + B 4 b128); BAR; 32 MFMA; BAR
//   p1: ds_read d0.kh1; BAR; 32 MFMA; BAR                      [d0 retired]
//   p2: stage t(2n+2)->d0; VMCNT(8) [drains t(2n+1)]; (last iter: VMCNT(0))
//       ds_read d1.kh0; BAR; 32 MFMA; BAR
//   p3: ds_read d1.kh1; BAR; 32 MFMA; BAR                      [d1 retired]
// 8 barriers/iter (was 16 in round 6) at identical DS/VMEM volume.
// MODE 1: encoder LSTM epilogue (+ hn capture + stage x[t+1])
// MODE 2: decoder LSTM epilogue (+ stage x[t])
// ============================================================================
#define REGION(dd, mat) (((dd)*2 + (mat)) * 16384)

#define STAGE(dd, mat, ktile) do { \
    const u16* Gp_ = (mat) ? W : A; \
    const int rb_ = (mat) ? bn : bm; \
    const int r0_ = tid >> 3; \
    const int ks_ = (ktile)*64 + (((tid & 7) ^ (r0_ & 7)) << 3); \
    u16* dst_ = &lds[REGION(dd, mat) + tid*8]; \
    const u16* s0_ = Gp_ + (size_t)(rb_ + r0_) * Kp + ks_; \
    gload_lds16(s0_,                    dst_); \
    gload_lds16(s0_ + (size_t)64  * Kp, dst_ + 4096); \
    gload_lds16(s0_ + (size_t)128 * Kp, dst_ + 8192); \
    gload_lds16(s0_ + (size_t)192 * Kp, dst_ + 12288); \
} while (0)

#define LDA8(dd, kh) do { \
    const u16* bp_ = &lds[REGION(dd, 0)]; \
    const int sw_ = ((((kh)*4 + (lane >> 4)) ^ (lane & 7)) << 3); \
    _Pragma("unroll") \
    for (int i_ = 0; i_ < 8; ++i_) \
        af[i_] = *(const bf16x8*)&bp_[(wm*128 + i_*16 + (lane & 15))*64 + sw_]; \
} while (0)

#define LDB4(dd, kh) do { \
    const u16* bp_ = &lds[REGION(dd, 1)]; \
    const int sw_ = ((((kh)*4 + (lane >> 4)) ^ (lane & 7)) << 3); \
    _Pragma("unroll") \
    for (int j_ = 0; j_ < 4; ++j_) \
        bf[j_] = *(const bf16x8*)&bp_[(wn*64 + j_*16 + (lane & 15))*64 + sw_]; \
} while (0)

#define MFMA32() do { \
    __builtin_amdgcn_s_setprio(1); \
    _Pragma("unroll") \
    for (int i_ = 0; i_ < 8; ++i_) \
    _Pragma("unroll") \
    for (int j_ = 0; j_ < 4; ++j_) \
        acc[i_][j_] = __builtin_amdgcn_mfma_f32_16x16x32_bf16( \
            af[i_], bf[j_], acc[i_][j_], 0, 0, 0); \
    __builtin_amdgcn_s_setprio(0); \
} while (0)

template<int MODE>
__global__ __launch_bounds__(512, 2)
void gemm256(const u16* __restrict__ A, const u16* __restrict__ W,
             int Kp, int NT, int H,
             float* __restrict__ Cst, u16* __restrict__ Aout,
             const float* __restrict__ bias, const int* __restrict__ lens,
             u16* __restrict__ HN, const float* __restrict__ X, int t)
{
    extern __shared__ u16 lds[];
    const int tid  = threadIdx.x;
    const int lane = tid & 63;
    const int wid  = tid >> 6;
    const int wm = wid >> 2, wn = wid & 3;
    const int bm = blockIdx.x * 256;
    const int bn = blockIdx.y * 256;

    f32x4 acc[8][4] = {};
    bf16x8 af[8], bf[4];

    // prologue: tile 0 -> d0 (full drain + barrier, clean t0 guarantee)
    STAGE(0, 0, 0); STAGE(0, 1, 0);
    VMCNT(0);
    BAR();

    const int NI = NT >> 1;
    for (int n = 0; n < NI; ++n) {
        const int t1 = 2*n + 1, t2 = 2*n + 2;
        const bool more = (t2 < NT);
        // p0: stage t1->d1; drain d0's loads; consume d0.kh0
        STAGE(1, 0, t1); STAGE(1, 1, t1);
        VMCNT(8);
        LDA8(0, 0); LDB4(0, 0);
        BAR(); MFMA32(); BAR();
        // p1: consume d0.kh1
        LDA8(0, 1); LDB4(0, 1);
        BAR(); MFMA32(); BAR();           // d0 retired
        // p2: stage t2->d0; drain d1's loads; consume d1.kh0
        if (more) { STAGE(0, 0, t2); STAGE(0, 1, t2); VMCNT(8); }
        else      { VMCNT(0); }
        LDA8(1, 0); LDB4(1, 0);
        BAR(); MFMA32(); BAR();
        // p3: consume d1.kh1
        LDA8(1, 1); LDB4(1, 1);
        BAR(); MFMA32(); BAR();           // d1 retired
    }

    // ---- fused LSTM epilogue (gate-interleaved weights) ----
    // acc[i] covers rows wm*128 + i*16 .. +15.
    const int hcol = ((bn >> 6) + wn) * 16 + (lane & 15);
    const float bI = bias[hcol];
    const float bF = bias[H + hcol];
    const float bG = bias[2 * H + hcol];
    const float bO = bias[3 * H + hcol];
#pragma unroll
    for (int i = 0; i < 8; ++i) {
        const int rbase = bm + wm * 128 + i * 16 + (lane >> 4) * 4;
#pragma unroll
        for (int q = 0; q < 4; ++q) {
            const int r = rbase + q;
            float iv = sigmf(acc[i][0][q] + bI);
            float fv = sigmf(acc[i][1][q] + bF);
            float gv = tanh_(acc[i][2][q] + bG);
            float ov = sigmf(acc[i][3][q] + bO);
            float cn = fv * Cst[(size_t)r * H + hcol] + iv * gv;
            float h  = ov * tanh_(cn);
            Cst[(size_t)r * H + hcol] = cn;
            Aout[(size_t)r * Kp + hcol] = f2bf(h);
            if (MODE == 1) {
                int L = lens[r]; L = (L < 1) ? 1 : (L > TT ? TT : L);
                if (t == L - 1) HN[(size_t)r * H + hcol] = f2bf(h);
            }
        }
    }
    // stage next-step x into Aout x-columns (one block column does it)
    const int tx = (MODE == 1) ? t + 1 : t;
    if (bn == 0 && tx < TT) {
        for (int ii = tid; ii < 256 * DD; ii += 512) {
            const int rr = ii / DD, d = ii - rr * DD;
            const int r = bm + rr;
            Aout[(size_t)r * Kp + H + d] = f2bf(X[((size_t)r * TT + tx) * DD + d]);
        }
    }
}

// ---------------- plain 128x128 GEMM (small matmuls): C = A * W^T ----------
__global__ __launch_bounds__(256, 2)
void gemm_bt(const u16* __restrict__ A, const u16* __restrict__ W,
             float* __restrict__ C, int N, int K)
{
    __shared__ u16 As[128 * 64];
    __shared__ u16 Ws[128 * 64];
    const int tid  = threadIdx.x;
    const int lane = tid & 63;
    const int wave = tid >> 6;
    const int wm = wave >> 1, wn = wave & 1;
    const int bm = blockIdx.x * 128;
    const int bn = blockIdx.y * 128;

    f32x4 acc[4][4] = {};
    const int lrow = lane >> 3;
    const int lcol = (lane & 7) * 8;

    for (int kt = 0; kt < K; kt += 64) {
#pragma unroll
        for (int c2 = 0; c2 < 4; ++c2) {
            const int chunk = wave * 4 + c2;
            const int row = chunk * 8 + lrow;
            gload_lds16(A + (size_t)(bm + row) * K + kt + lcol, &As[chunk * 512]);
            gload_lds16(W + (size_t)(bn + row) * K + kt + lcol, &Ws[chunk * 512]);
        }
        __syncthreads();
#pragma unroll
        for (int ks = 0; ks < 2; ++ks) {
            bf16x8 af[4], wf[4];
            const int ko = ks * 32 + (lane >> 4) * 8;
            const int rA = wm * 64 + (lane & 15);
            const int rW = wn * 64 + (lane & 15);
#pragma unroll
            for (int i = 0; i < 4; ++i)
                af[i] = *(const bf16x8*)&As[(rA + i * 16) * 64 + ko];
#pragma unroll
            for (int i = 0; i < 4; ++i)
                wf[i] = *(const bf16x8*)&Ws[(rW + i * 16) * 64 + ko];
#pragma unroll
            for (int i = 0; i < 4; ++i)
#pragma unroll
                for (int j = 0; j < 4; ++j)
                    acc[i][j] = __builtin_amdgcn_mfma_f32_16x16x32_bf16(
                        af[i], wf[j], acc[i][j], 0, 0, 0);
        }
        __syncthreads();
    }
    const int r0 = bm + wm * 64 + (lane >> 4) * 4;
    const int c0 = bn + wn * 64 + (lane & 15);
#pragma unroll
    for (int i = 0; i < 4; ++i)
#pragma unroll
        for (int j = 0; j < 4; ++j) {
            float* Cp = C + (size_t)(r0 + i * 16) * N + c0 + j * 16;
#pragma unroll
            for (int q = 0; q < 4; ++q)
                Cp[(size_t)q * N] = acc[i][j][q];
        }
}

// ---------------- gate-interleaved weight concat (padded K) ----------------
// n' = 64*(j>>4) + 16*gate + (j&15); row = [Whh[gate*H+j] | Wih[gate*H+j] | 0]
__global__ void prep_wg(const float* __restrict__ Whh, const float* __restrict__ Wih,
                        u16* __restrict__ dst, int H, int Kc, int total)
{
    int idx = blockIdx.x * 256 + threadIdx.x;
    if (idx >= total) return;
    int np = idx / Kc, k = idx - np * Kc;
    int jblk = np >> 6, rem = np & 63;
    int gate = rem >> 4, jl = rem & 15;
    int j = jblk * 16 + jl;
    int srow = gate * H + j;
    float v = 0.f;
    if (k < H) v = Whh[(size_t)srow * H + k];
    else if (k < H + DD) v = Wih[srow * DD + (k - H)];
    dst[idx] = f2bf(v);
}

// ---------------- plain stacked concat (bf16): [W0; W1] ----------------
__global__ void prep_cat(const float* __restrict__ W0, const float* __restrict__ W1,
                         u16* __restrict__ dst, int rows0, int K, int total)
{
    int idx = blockIdx.x * 256 + threadIdx.x;
    if (idx >= total) return;
    int n = idx / K, k = idx - n * K;
    float v = (n < rows0) ? W0[(size_t)n * K + k] : W1[(size_t)(n - rows0) * K + k];
    dst[idx] = f2bf(v);
}

__global__ void prep_bf(const float* __restrict__ src, u16* __restrict__ dst, int total)
{
    int idx = blockIdx.x * 256 + threadIdx.x;
    if (idx < total) dst[idx] = f2bf(src[idx]);
}

// ---------------- encoder init: h=0, x col = x[:,0,:], pad=0; c=0 ----------
__global__ void init_enc(u16* __restrict__ A, float* __restrict__ c, const float* __restrict__ x)
{
    int idx = blockIdx.x * 256 + threadIdx.x;   // BB*KEp
    int b = idx / KEp, j = idx - b * KEp;
    u16 v = 0;
    if (j >= HE && j < HE + DD) v = f2bf(x[(size_t)b * (TT * DD) + (j - HE)]);
    A[idx] = v;
    if (j < HE) c[(size_t)b * HE + j] = 0.f;
}

// ---------------- zero pad columns [lo, lo+n) of A[BB][ldK] ----------------
__global__ void zero_pads(u16* __restrict__ A, int ldK, int lo, int n, int total)
{
    int idx = blockIdx.x * 256 + threadIdx.x;
    if (idx >= total) return;
    int b = idx / n, j = idx - b * n;
    A[(size_t)b * ldK + lo + j] = 0;
}

// ---------------- z from MV = [mu | lv] fp32 ----------------
__global__ void z_comp(const float* __restrict__ MV, const float* __restrict__ bmu,
                       const float* __restrict__ blv, const float* __restrict__ eps,
                       float* __restrict__ out, u16* __restrict__ Zbf)
{
    int idx = blockIdx.x * 256 + threadIdx.x;   // BB*ZZ
    int b = idx >> 7, zc = idx & (ZZ - 1);
    float mu = MV[(size_t)b * 256 + zc] + bmu[zc];
    float lv = MV[(size_t)b * 256 + ZZ + zc] + blv[zc];
    float z = mu + eps[idx] * __expf(0.5f * lv);
    const size_t XR = (size_t)BB * TT * DD;
    out[XR + idx] = mu;
    out[XR + (size_t)BB * ZZ + idx] = lv;
    out[XR + 2 * (size_t)BB * ZZ + idx] = z;
    Zbf[idx] = f2bf(z);
}

// ---------------- decoder state init from HC = [h0pre | c0pre] -------------
__global__ void hc_init(const float* __restrict__ HC, const float* __restrict__ bh0,
                        const float* __restrict__ bc0, u16* __restrict__ A,
                        float* __restrict__ c)
{
    int idx = blockIdx.x * 256 + threadIdx.x;   // BB*HD
    int b = idx >> 10, j = idx & (HD - 1);
    float h0 = tanh_(HC[(size_t)b * 2048 + j] + bh0[j]);
    float c0 = tanh_(HC[(size_t)b * 2048 + HD + j] + bc0[j]);
    A[(size_t)b * KDp + j] = f2bf(h0);
    c[idx] = c0;
}

// ---------------- decoder x-col init: start token + zero pad to KDp --------
__global__ void init_dec(u16* __restrict__ A, const float* __restrict__ st)
{
    int idx = blockIdx.x * 256 + threadIdx.x;   // BB*128
    int b = idx >> 7, j = idx & 127;
    A[(size_t)b * KDp + HD + j] = (j < DD) ? f2bf(st[j]) : (u16)0;
}

// ---------------- output projection: wave per row, butterfly reduce --------
__global__ void outproj2(const u16* __restrict__ A, const u16* __restrict__ Wb,
                         const float* __restrict__ bout, float* __restrict__ xr, int t)
{
    int gid = blockIdx.x * 256 + threadIdx.x;
    int b = gid >> 6;
    int lane = threadIdx.x & 63;
    const u16* h = A + (size_t)b * KDp;
    const int k0 = lane * 16;
    bf16x8 h0 = *(const bf16x8*)&h[k0];
    bf16x8 h1 = *(const bf16x8*)&h[k0 + 8];
    float hv[16];
#pragma unroll
    for (int k = 0; k < 8; ++k) { hv[k] = bf2f((u16)h0[k]); hv[k + 8] = bf2f((u16)h1[k]); }
    float acc[DD];
#pragma unroll
    for (int d = 0; d < DD; ++d) {
        const u16* w = Wb + d * HD + k0;
        bf16x8 w0 = *(const bf16x8*)&w[0];
        bf16x8 w1 = *(const bf16x8*)&w[8];
        float a = 0.f;
#pragma unroll
        for (int k = 0; k < 8; ++k)
            a += hv[k] * bf2f((u16)w0[k]) + hv[k + 8] * bf2f((u16)w1[k]);
        acc[d] = a;
    }
#pragma unroll
    for (int off = 32; off > 0; off >>= 1)
#pragma unroll
        for (int d = 0; d < DD; ++d)
            acc[d] += __shfl_xor(acc[d], off);
    if (lane < DD)
        xr[((size_t)b * TT + t) * DD + lane] = acc[lane] + bout[lane];
}

// ---------------- launch ----------------
extern "C" void kernel_launch(void* const* d_in, const int* in_sizes, int n_in,
                              void* d_out, int out_size, void* d_ws, size_t ws_size,
                              hipStream_t stream)
{
    const float* x    = (const float*)d_in[0];
    const int*   lens = (const int*)d_in[1];
    const float* eps  = (const float*)d_in[2];
    const float* Wihe = (const float*)d_in[3];
    const float* Whhe = (const float*)d_in[4];
    const float* be   = (const float*)d_in[5];
    const float* Wmu  = (const float*)d_in[6];
    const float* bmu  = (const float*)d_in[7];
    const float* Wlv  = (const float*)d_in[8];
    const float* blv  = (const float*)d_in[9];
    const float* Wh0  = (const float*)d_in[10];
    const float* bh0  = (const float*)d_in[11];
    const float* Wc0  = (const float*)d_in[12];
    const float* bc0  = (const float*)d_in[13];
    const float* st   = (const float*)d_in[14];
    const float* Wihd = (const float*)d_in[15];
    const float* Whhd = (const float*)d_in[16];
    const float* bd   = (const float*)d_in[17];
    const float* Wout = (const float*)d_in[18];
    const float* bout = (const float*)d_in[19];
    float* out = (float*)d_out;

    char* ws = (char*)d_ws;
    size_t o = 0;
    u16*   WCE = (u16*)(ws + o); o += (size_t)2048 * KEp * 2;  //  2,621,440
    u16*   WCD = (u16*)(ws + o); o += (size_t)4096 * KDp * 2;  //  9,437,184
    u16*   WMV = (u16*)(ws + o); o += (size_t)256 * 512 * 2;   //    262,144
    u16*   WHC = (u16*)(ws + o); o += (size_t)2048 * 128 * 2;  //    524,288
    u16*   WOB = (u16*)(ws + o); o += 32768;
    u16*   AE0 = (u16*)(ws + o); o += (size_t)BB * KEp * 2;    // 10,485,760
    u16*   AE1 = (u16*)(ws + o); o += (size_t)BB * KEp * 2;
    u16*   AD0 = (u16*)(ws + o); o += (size_t)BB * KDp * 2;    // 18,874,368
    u16*   AD1 = (u16*)(ws + o); o += (size_t)BB * KDp * 2;
    float* CE  = (float*)(ws + o); o += (size_t)BB * HE * 4;   // 16,777,216
    float* CD  = (float*)(ws + o); o += (size_t)BB * HD * 4;   // 33,554,432
    u16*   HNb = (u16*)(ws + o); o += (size_t)BB * HE * 2;     //  8,388,608
    float* MV  = (float*)(ws + o); o += (size_t)BB * 256 * 4;  //  8,388,608
    u16*   Zbf = (u16*)(ws + o); o += (size_t)BB * ZZ * 2;     //  2,097,152
    float* HC  = (float*)(ws + o); o += (size_t)BB * 2048 * 4; // 67,108,864
    // total ~216 MB

    hipFuncSetAttribute((const void*)gemm256<1>,
                        hipFuncAttributeMaxDynamicSharedMemorySize, 131072);
    hipFuncSetAttribute((const void*)gemm256<2>,
                        hipFuncAttributeMaxDynamicSharedMemorySize, 131072);

    prep_wg<<<(2048 * KEp + 255) / 256, 256, 0, stream>>>(Whhe, Wihe, WCE, HE, KEp, 2048 * KEp);
    prep_wg<<<(4096 * KDp + 255) / 256, 256, 0, stream>>>(Whhd, Wihd, WCD, HD, KDp, 4096 * KDp);
    prep_cat<<<(256 * 512 + 255) / 256, 256, 0, stream>>>(Wmu, Wlv, WMV, ZZ, HE, 256 * 512);
    prep_cat<<<(2048 * 128 + 255) / 256, 256, 0, stream>>>(Wh0, Wc0, WHC, HD, ZZ, 2048 * 128);
    prep_bf<<<(12 * HD + 255) / 256, 256, 0, stream>>>(Wout, WOB, 12 * HD);
    init_enc<<<(BB * KEp) / 256, 256, 0, stream>>>(AE0, CE, x);
    zero_pads<<<(BB * 116 + 255) / 256, 256, 0, stream>>>(AE1, KEp, HE + DD, 116, BB * 116);
    zero_pads<<<(BB * 116 + 255) / 256, 256, 0, stream>>>(AD1, KDp, HD + DD, 116, BB * 116);

    u16* AE[2] = {AE0, AE1};
    for (int t = 0; t < TT; ++t) {
        gemm256<1><<<dim3(BB / 256, 2048 / 256), 512, 131072, stream>>>(
            AE[t & 1], WCE, KEp, 10, HE, CE, AE[1 - (t & 1)], be, lens, HNb, x, t);
    }

    gemm_bt<<<dim3(BB / 128, 256 / 128), 256, 0, stream>>>(HNb, WMV, MV, 256, 512);
    z_comp<<<(BB * ZZ) / 256, 256, 0, stream>>>(MV, bmu, blv, eps, out, Zbf);
    gemm_bt<<<dim3(BB / 128, 2048 / 128), 256, 0, stream>>>(Zbf, WHC, HC, 2048, 128);
    hc_init<<<(BB * HD) / 256, 256, 0, stream>>>(HC, bh0, bc0, AD0, CD);
    init_dec<<<(BB * 128) / 256, 256, 0, stream>>>(AD0, st);

    u16* AD[2] = {AD0, AD1};
    for (int t = 0; t < TT; ++t) {
        gemm256<2><<<dim3(BB / 256, 4096 / 256), 512, 131072, stream>>>(
            AD[t & 1], WCD, KDp, 18, HD, CD, AD[1 - (t & 1)], bd, nullptr, nullptr, x, t);
        outproj2<<<(BB * 64) / 256, 256, 0, stream>>>(AD[1 - (t & 1)], WOB, bout, out, t);
    }
}